// Round 8
// baseline (1425.409 us; speedup 1.0000x reference)
//
#include <hip/hip_runtime.h>

using u16 = unsigned short;
using u32 = unsigned int;

typedef short s16x8 __attribute__((ext_vector_type(8)));
typedef float f32x4 __attribute__((ext_vector_type(4)));

static __device__ __forceinline__ float b2f(u16 u){ u32 x = ((u32)u) << 16; float f; __builtin_memcpy(&f, &x, 4); return f; }
static __device__ __forceinline__ u16 f2bf(float f){ u32 x; __builtin_memcpy(&x, &f, 4); x += 0x7fffu + ((x >> 16) & 1u); return (u16)(x >> 16); }

static __device__ __forceinline__ void async16(const u16* g, u16* l){
  __builtin_amdgcn_global_load_lds((const __attribute__((address_space(1))) u32*)g,
                                   (__attribute__((address_space(3))) u32*)l, 16, 0, 0);
}

// ---------------------------------------------------------------------------
__global__ void detect_flags(const u16* x, const int* ei, int* flags){
  if (blockIdx.x || threadIdx.x) return;
  int cf = 0;
  for (int i = 0; i < 128; ++i){
    int ex = (x[2*i] >> 7) & 0xff;
    if (ex >= 110 && ex <= 140) cf++;
  }
  flags[0] = (cf > 64) ? 1 : 0;
  int cz = 0;
  for (int i = 0; i < 128; ++i){ if (ei[2*i+1] != 0) cz++; }
  flags[1] = (cz > 64) ? 1 : 0;
}

__global__ void zero_u32(u32* p, int n){
  int i = blockIdx.x*256 + threadIdx.x;
  if (i < n) p[i] = 0;
}

__global__ void pad_copy_x(const void* xin, u16* xp, int Nreal, long tot, int F, int Fp, const int* flags){
  long idx = (long)blockIdx.x*256 + threadIdx.x;
  if (idx >= tot) return;
  int n = (int)(idx / Fp), f = (int)(idx - (long)n*Fp);
  u16 v = 0;
  if (n < Nreal && f < F){
    if (flags[0]) v = ((const u16*)xin)[(long)n*F + f];
    else          v = f2bf(((const float*)xin)[(long)n*F + f]);
  }
  xp[idx] = v;
}

__global__ void transpose_pad(const void* W, u16* Wt, int K, int Nsub, int Kp, int Np,
                              int ldW, int colOff, const int* flags){
  __shared__ u16 tile[32][33];
  int f0 = flags[0];
  int kb = blockIdx.x*32, nb = blockIdx.y*32;
  int tx = threadIdx.x & 31, ty = threadIdx.x >> 5;
  for (int dy = 0; dy < 32; dy += 8){
    int k = kb + dy + ty, n = nb + tx;
    u16 v = 0;
    if (k < K && n < Nsub){
      long src = (long)k*ldW + colOff + n;
      if (f0) v = ((const u16*)W)[src];
      else    v = f2bf(((const float*)W)[src]);
    }
    tile[dy+ty][tx] = v;
  }
  __syncthreads();
  for (int dy = 0; dy < 32; dy += 8){
    int n = nb + dy + ty, k = kb + tx;
    if (n < Np && k < Kp) Wt[(long)n*Kp + k] = tile[tx][dy+ty];
  }
}

// five bias-style vectors in one launch
__global__ void copy_vec5(const void* s0, u16* d0, int n0,
                          const void* s1, u16* d1, int n1,
                          const void* s2, u16* d2, int n2,
                          const void* s3, u16* d3, int n3,
                          const void* s4, u16* d4, int n4,
                          const int* flags){
  int i = blockIdx.x*256 + threadIdx.x;
  int f0 = flags[0];
  auto cv = [&](const void* s, int j)->u16{
    return f0 ? ((const u16*)s)[j] : f2bf(((const float*)s)[j]);
  };
  if (i < n0){ d0[i] = cv(s0, i); return; } i -= n0;
  if (i < n1){ d1[i] = cv(s1, i); return; } i -= n1;
  if (i < n2){ d2[i] = cv(s2, i); return; } i -= n2;
  if (i < n3){ d3[i] = cv(s3, i); return; } i -= n3;
  if (i < n4){ d4[i] = cv(s4, i); }
}

// rowC/colC/bat32 in one launch
__global__ void copy_int3(const int* ei, const int* bat,
                          int* rowC, int* colC, int* bat32,
                          int E, int N, const int* flags){
  int i = blockIdx.x*256 + threadIdx.x;
  int f1 = flags[1];
  if (i < E){ rowC[i] = f1 ? ei[i] : ei[2*i]; return; } i -= E;
  if (i < E){ colC[i] = f1 ? ei[E + i] : ei[2*(E + i)]; return; } i -= E;
  if (i < N){ bat32[i] = f1 ? bat[i] : bat[2*i]; }
}

// ---------------------------------------------------------------------------
// CSR build
__global__ void hist_kernel(const int* __restrict__ colC, u32* cnt, int E){
  int e = blockIdx.x*256 + threadIdx.x;
  if (e < E) atomicAdd(&cnt[colC[e]], 1u);
}

__global__ void scan_local(const u32* __restrict__ cnt, u32* __restrict__ rowptr,
                           u32* __restrict__ bsum, int N){
  int blk = blockIdx.x, t = threadIdx.x;
  int i = blk*1024 + t;
  u32 v = (i < N) ? (cnt[i] + 1u) : 0u;
  u32 x = v;
  for (int off = 1; off < 64; off <<= 1){
    u32 y = __shfl_up(x, off);
    if ((t & 63) >= off) x += y;
  }
  __shared__ u32 ws[16];
  if ((t & 63) == 63) ws[t >> 6] = x;
  __syncthreads();
  if (t < 16){
    u32 y = ws[t];
    for (int off = 1; off < 16; off <<= 1){
      u32 z = __shfl_up(y, off);
      if (t >= off) y += z;
    }
    ws[t] = y;
  }
  __syncthreads();
  u32 base = (t >> 6) ? ws[(t >> 6) - 1] : 0u;
  u32 inc = base + x;
  if (i < N) rowptr[i + 1] = inc;
  if (t == 1023) bsum[blk] = inc;
}

__global__ void scan_bsums(const u32* __restrict__ bsum, u32* __restrict__ boff, int nb){
  int t = threadIdx.x;
  u32 v = (t < nb) ? bsum[t] : 0u;
  u32 x = v;
  for (int off = 1; off < 64; off <<= 1){
    u32 y = __shfl_up(x, off);
    if ((t & 63) >= off) x += y;
  }
  __shared__ u32 ws[16];
  if ((t & 63) == 63) ws[t >> 6] = x;
  __syncthreads();
  if (t < 16){
    u32 y = ws[t];
    for (int off = 1; off < 16; off <<= 1){
      u32 z = __shfl_up(y, off);
      if (t >= off) y += z;
    }
    ws[t] = y;
  }
  __syncthreads();
  u32 base = (t >> 6) ? ws[(t >> 6) - 1] : 0u;
  u32 inc = base + x;
  if (t < nb) boff[t] = inc - v;
}

__global__ void scan_fixup(u32* rowptr, const u32* __restrict__ boff, int N){
  int i = blockIdx.x*1024 + threadIdx.x;
  if (i < N) rowptr[i+1] += boff[blockIdx.x];
  if (i == 0) rowptr[0] = 0;
}

__global__ void fill_self(const u32* rowptr, int* eidx, u32* cursor, int N){
  int i = blockIdx.x*256 + threadIdx.x;
  if (i >= N) return;
  eidx[rowptr[i]] = i;
  cursor[i] = rowptr[i] + 1;
}

__global__ void fill_edges(const int* __restrict__ rowC, const int* __restrict__ colC,
                           u32* cursor, int* eidx, int E){
  int e = blockIdx.x*256 + threadIdx.x;
  if (e >= E) return;
  u32 pos = atomicAdd(&cursor[colC[e]], 1u);
  eidx[pos] = rowC[e];
}

// ---------------------------------------------------------------------------
__global__ void wproj(const void* W, const void* as, const void* ad,
                      float* wsrc, float* wdst, int Cin, int Cpad, int Chead, int ldW,
                      const int* flags){
  int h = blockIdx.y;
  int c = blockIdx.x*256 + threadIdx.x;
  if (c >= Cpad) return;
  int f0 = flags[0];
  float s = 0.f, d = 0.f;
  if (c < Cin){
    long base = (long)c*ldW + (long)h*Chead;
    for (int o = 0; o < Chead; ++o){
      float wv = f0 ? b2f(((const u16*)W)[base+o]) : ((const float*)W)[base+o];
      float av = f0 ? b2f(((const u16*)as)[h*Chead+o]) : ((const float*)as)[h*Chead+o];
      float dv = f0 ? b2f(((const u16*)ad)[h*Chead+o]) : ((const float*)ad)[h*Chead+o];
      s += wv*av; d += wv*dv;
    }
  }
  wsrc[h*Cpad+c] = s; wdst[h*Cpad+c] = d;
}

template<int H>
__global__ void attn_dots_v(const u16* __restrict__ xin, long ldx,
                            const float* __restrict__ wsrc, const float* __restrict__ wdst,
                            float* __restrict__ a_src, float* __restrict__ a_dst,
                            int Nn, int C){
  int node = blockIdx.x*4 + (threadIdx.x >> 6);
  if (node >= Nn) return;
  int lane = threadIdx.x & 63;
  const u16* xr = xin + (long)node*ldx;
  float s[H], d[H];
#pragma unroll
  for (int h = 0; h < H; ++h){ s[h] = 0.f; d[h] = 0.f; }
  for (int c = lane*8; c < C; c += 512){
    s16x8 xv = *(const s16x8*)&xr[c];
    float xf[8];
#pragma unroll
    for (int j = 0; j < 8; ++j) xf[j] = b2f((u16)xv[j]);
#pragma unroll
    for (int h = 0; h < H; ++h){
      f32x4 w0 = *(const f32x4*)&wsrc[h*C + c];
      f32x4 w1 = *(const f32x4*)&wsrc[h*C + c + 4];
      f32x4 d0 = *(const f32x4*)&wdst[h*C + c];
      f32x4 d1 = *(const f32x4*)&wdst[h*C + c + 4];
#pragma unroll
      for (int j = 0; j < 4; ++j){
        s[h] += xf[j]*w0[j] + xf[j+4]*w1[j];
        d[h] += xf[j]*d0[j] + xf[j+4]*d1[j];
      }
    }
  }
#pragma unroll
  for (int h = 0; h < H; ++h)
    for (int off = 32; off; off >>= 1){ s[h] += __shfl_down(s[h], off); d[h] += __shfl_down(d[h], off); }
  if (lane == 0){
#pragma unroll
    for (int h = 0; h < H; ++h){ a_src[(long)node*H+h] = s[h]; a_dst[(long)node*H+h] = d[h]; }
  }
}

__global__ void attn_stats(const u32* __restrict__ rowptr, const int* __restrict__ eidx,
                           const float* __restrict__ a_src, const float* __restrict__ a_dst,
                           u16* __restrict__ pbuf, float* __restrict__ invd, int NH, int H){
  int idx = blockIdx.x*256 + threadIdx.x;
  if (idx >= NH) return;
  int i = idx / H, hd = idx - i*H;
  u32 s0 = rowptr[i], s1 = rowptr[i+1];
  float ad = a_dst[idx];
  float m = -1e30f;
  for (u32 p = s0; p < s1; ++p){
    float e = a_src[eidx[p]*H + hd] + ad;
    e = e > 0.f ? e : 0.2f*e;
    m = fmaxf(m, e);
  }
  float den = 0.f;
  for (u32 p = s0; p < s1; ++p){
    float e = a_src[eidx[p]*H + hd] + ad;
    e = e > 0.f ? e : 0.2f*e;
    float v = __expf(e - m);
    pbuf[(long)p*H + hd] = f2bf(v);
    den += v;
  }
  invd[idx] = 1.f / (den + 1e-16f);
}

__global__ void aggregate_v(const u32* __restrict__ rowptr, const int* __restrict__ eidx,
                            const u16* __restrict__ pbuf, const float* __restrict__ invd,
                            const u16* __restrict__ xin, long ldx,
                            u16* __restrict__ xagg, long ldagg,
                            int chunks, int H, int headStride){
  int i = blockIdx.x;
  int t = threadIdx.x;
  if (t >= H*chunks) return;
  int h = t / chunks, ck = t - h*chunks;
  int c0 = ck*8;
  u32 s0 = rowptr[i], s1 = rowptr[i+1];
  float acc[8];
#pragma unroll
  for (int j = 0; j < 8; ++j) acc[j] = 0.f;
  int src = eidx[s0];
  for (u32 p = s0; p < s1; ++p){
    int nsrc = (p+1 < s1) ? eidx[p+1] : 0;
    float wgt = b2f(pbuf[(long)p*H + h]);
    s16x8 v = *(const s16x8*)&xin[(long)src*ldx + c0];
#pragma unroll
    for (int j = 0; j < 8; ++j) acc[j] += wgt * b2f((u16)v[j]);
    src = nsrc;
  }
  float inv = invd[(long)i*H + h];
  s16x8 ov;
#pragma unroll
  for (int j = 0; j < 8; ++j) ov[j] = (short)f2bf(acc[j]*inv);
  *(s16x8*)&xagg[(long)i*ldagg + h*headStride + c0] = ov;
}

__global__ void pack_pool(const u32* __restrict__ poolf, u16* __restrict__ pooled, int n){
  int i = blockIdx.x*256 + threadIdx.x;
  if (i >= n) return;
  u32 b = poolf[i]; float f; __builtin_memcpy(&f, &b, 4);
  pooled[i] = f2bf(f);
}

// ---------------------------------------------------------------------------
// Multi-head batched GEMM: for head h, C_h[M,Nstore] = A_h[M,K](lda) @ B_h[*,K]^T.
// A_h = Ag + h*hA, B_h = Bg + h*hB, bias_h = bias + h*hC, C_h = Cg + h*hC.
// 1D grid, XCD-aware decode: all (head, ntile) of one M-group land on one XCD.
// BK=32 K-loop (R6-verified). K must be mult of 32 (B K-pad rows zeroed).
// mode bit0: bias+relu; bit1: store dtype per flags[0]; bit2: fused graph-max-pool.
__global__ __launch_bounds__(256) void gemm_bt(
    const u16* __restrict__ Ag, long lda, const u16* __restrict__ Bg,
    const u16* __restrict__ bias, u16* __restrict__ Cg,
    int M, int Nstore, int K, long ldc, int mode, const int* flags,
    const int* __restrict__ batg, u32* poolf, long ldp,
    int nt, int mt, int nh, long hA, long hB, long hC)
{
  const int xcd = blockIdx.x & 7;
  const int g = blockIdx.x >> 3;
  const int nhnt = nh * nt;
  const int inner = g % nhnt;
  const int ntile = inner % nt;
  const int head  = inner / nt;
  const int m = (g / nhnt)*8 + xcd;
  if (m >= mt) return;

  const u16* A  = Ag + (long)head*hA;
  const u16* B  = Bg + (long)head*hB;
  const u16* bi = bias + (long)head*hC;
  u16* C        = Cg + (long)head*hC;

  __shared__ __align__(16) u16 As[128*32];
  __shared__ __align__(16) u16 Bs[128*32];
  const int tid = threadIdx.x;
  const int wave = tid >> 6, lane = tid & 63;
  const int quad = lane >> 4, mrow = lane & 15;
  const int wm = (wave >> 1) * 64, wn = (wave & 1) * 64;
  const long bm = (long)m * 128;
  const long bn = (long)ntile * 128;

  f32x4 acc[4][4];
#pragma unroll
  for (int i = 0; i < 4; i++)
#pragma unroll
    for (int j = 0; j < 4; j++) acc[i][j] = (f32x4){0.f, 0.f, 0.f, 0.f};

  const int r0 = wave*32 + (lane >> 2);
  const int r1 = r0 + 16;
  const int kcl = lane & 3;
  const int q0 = kcl ^ ((r0 >> 1) & 3);
  const int q1 = kcl ^ ((r1 >> 1) & 3);
  const u16* a0 = A + (bm + r0)*lda + q0*8;
  const u16* a1 = A + (bm + r1)*lda + q1*8;
  const u16* b0 = B + (bn + r0)*(long)K + q0*8;
  const u16* b1 = B + (bn + r1)*(long)K + q1*8;
  u16* la0 = &As[r0*32 + kcl*8];
  u16* la1 = &As[r1*32 + kcl*8];
  u16* lb0 = &Bs[r0*32 + kcl*8];
  u16* lb1 = &Bs[r1*32 + kcl*8];

  for (int k0 = 0; k0 < K; k0 += 32){
    async16(a0 + k0, la0);
    async16(a1 + k0, la1);
    async16(b0 + k0, lb0);
    async16(b1 + k0, lb1);
    __syncthreads();
    s16x8 af[4], bf[4];
#pragma unroll
    for (int i = 0; i < 4; i++){
      int r = wm + i*16 + mrow;
      int q = quad ^ ((r >> 1) & 3);
      af[i] = *(const s16x8*)&As[r*32 + q*8];
    }
#pragma unroll
    for (int j = 0; j < 4; j++){
      int r = wn + j*16 + mrow;
      int q = quad ^ ((r >> 1) & 3);
      bf[j] = *(const s16x8*)&Bs[r*32 + q*8];
    }
#pragma unroll
    for (int i = 0; i < 4; i++)
#pragma unroll
      for (int j = 0; j < 4; j++)
        acc[i][j] = __builtin_amdgcn_mfma_f32_16x16x32_bf16(af[i], bf[j], acc[i][j], 0, 0, 0);
    __syncthreads();
  }

  if (mode & 4){
    int garr[16];
#pragma unroll
    for (int i = 0; i < 4; i++)
#pragma unroll
      for (int r = 0; r < 4; r++){
        long row = bm + wm + i*16 + quad*4 + r;
        garr[i*4+r] = (row < M) ? batg[row] : -1;
      }
#pragma unroll
    for (int j = 0; j < 4; j++){
      long col = bn + wn + j*16 + mrow;
      if (col >= Nstore) continue;
      float bv = b2f(bi[col]);
      int curg = -1; float curm = 0.f;
#pragma unroll
      for (int i = 0; i < 4; i++)
#pragma unroll
        for (int r = 0; r < 4; r++){
          int g2 = garr[i*4+r];
          if (g2 >= 0){
            float v = fmaxf(acc[i][j][r] + bv, 0.f);
            if (g2 != curg){
              if (curg >= 0){
                u32 bits; __builtin_memcpy(&bits, &curm, 4);
                atomicMax(&poolf[(long)curg*ldp + col], bits);
              }
              curg = g2; curm = v;
            } else curm = fmaxf(curm, v);
          }
        }
      if (curg >= 0){
        u32 bits; __builtin_memcpy(&bits, &curm, 4);
        atomicMax(&poolf[(long)curg*ldp + col], bits);
      }
    }
    return;
  }

  const int f0 = (mode & 2) ? flags[0] : 1;
#pragma unroll
  for (int i = 0; i < 4; i++){
    long row0 = bm + wm + i*16 + quad*4;
#pragma unroll
    for (int j = 0; j < 4; j++){
      long col = bn + wn + j*16 + mrow;
      if (col < Nstore){
        float bv = (mode & 1) ? b2f(bi[col]) : 0.f;
#pragma unroll
        for (int r = 0; r < 4; r++){
          long row = row0 + r;
          if (row < M){
            float v = acc[i][j][r];
            if (mode & 1) v = fmaxf(v + bv, 0.f);
            if (f0) C[row*ldc + col] = f2bf(v);
            else    ((float*)C)[row*ldc + col] = v;
          }
        }
      }
    }
  }
}

// ---------------------------------------------------------------------------
extern "C" void kernel_launch(void* const* d_in, const int* in_sizes, int n_in,
                              void* d_out, int out_size, void* d_ws, size_t ws_size,
                              hipStream_t stream){
  const u16* x    = (const u16*)d_in[0];
  const int* ei   = (const int*)d_in[1];
  const int* bat  = (const int*)d_in[2];
  const void* W1  = d_in[3];
  const void* as1 = d_in[4]; const void* ad1 = d_in[5]; const void* b1 = d_in[6];
  const void* W2  = d_in[7];
  const void* as2 = d_in[8]; const void* ad2 = d_in[9]; const void* b2 = d_in[10];
  const void* W3  = d_in[11];
  const void* as3 = d_in[12]; const void* ad3 = d_in[13]; const void* b3 = d_in[14];
  const void* fc1w = d_in[15]; const void* fc1b = d_in[16];
  const void* fc2w = d_in[17]; const void* fc2b = d_in[18];

  const int E = in_sizes[1] / 2;
  const int N = in_sizes[2];
  const int G = 512, H = 4;
  const int Mpad = ((N + 127)/128)*128;
  const int Etot = E + N;
  const int Mt = Mpad/128;                 // 391
  const int nb1024 = (N + 1023)/1024;
  const int Mg8 = ((Mt + 7)/8);            // 49 M-groups of 8

  char* w = (char*)d_ws;
  size_t off = 0;
  auto AL = [&](size_t b)->char*{ char* p = w + off; off = (off + b + 255) & ~(size_t)255; return p; };

  u16* P = (u16*)AL((size_t)Mpad*1248*2 + 512);
  u16* Q = (u16*)AL((size_t)Mpad*1248*2 + 512);
  u16* wt1 = (u16*)AL((size_t)4*128*96*2);       // per-head [128 rows, K=96]
  u16* wt2 = (u16*)AL((size_t)4*384*320*2);      // per-head [384 rows, K=320]
  u16* wt3 = (u16*)AL((size_t)1280*1248*2);      // [1280 rows, K=1248]
  u16* wf1 = (u16*)AL((size_t)1024*1248*2);      // [1024 rows, K=1248]
  u16* wf2 = (u16*)AL((size_t)128*1024*2);       // [128 rows, K=1024]
  u16* cb1 = (u16*)AL(312*2);  u16* cb2 = (u16*)AL(1248*2); u16* cb3 = (u16*)AL(1248*2);
  u16* cbf1 = (u16*)AL(1024*2); u16* cbf2 = (u16*)AL(128*2);
  float* ws1 = (float*)AL(4*80*4);   float* wd1 = (float*)AL(4*80*4);
  float* ws2 = (float*)AL(4*312*4);  float* wd2 = (float*)AL(4*312*4);
  float* ws3 = (float*)AL(1248*4);   float* wd3 = (float*)AL(1248*4);
  float* a_src = (float*)AL((size_t)N*H*4);
  float* a_dst = (float*)AL((size_t)N*H*4);
  float* invd  = (float*)AL((size_t)N*H*4);
  u16*  pbuf   = (u16*)AL((size_t)Etot*H*2);
  u32* cnt     = (u32*)AL((size_t)N*4);
  u32* rowptr  = (u32*)AL((size_t)(N+1)*4);
  u32* bsum    = (u32*)AL((size_t)1024*4);
  u32* boff    = (u32*)AL((size_t)1024*4);
  int* eidx    = (int*)AL((size_t)Etot*4);
  int* bat32   = (int*)AL((size_t)N*4);
  u32* poolf   = (u32*)AL((size_t)G*1248*4);
  u16* pooled  = (u16*)AL((size_t)G*1248*2 + 512);
  u16* fc1o    = (u16*)AL((size_t)G*1024*2 + 512);
  int* flags   = (int*)AL(16);

  if (ws_size < off || n_in < 19) return;

  u16* xpad = (u16*)((char*)P + ((size_t)40 << 20));
  int* rowC = (int*)((char*)Q + ((size_t)64 << 20));
  int* colC = rowC + E;

  // ---- ingest ----
  detect_flags<<<1, 64, 0, stream>>>(x, ei, flags);
  zero_u32<<<(N+255)/256, 256, 0, stream>>>(cnt, N);
  zero_u32<<<(G*1248+255)/256, 256, 0, stream>>>(poolf, G*1248);
  {
    long tot = (long)Mpad*96;
    pad_copy_x<<<(unsigned)((tot+255)/256), 256, 0, stream>>>(x, xpad, N, tot, 78, 96, flags);
  }
  for (int h = 0; h < 4; ++h)
    transpose_pad<<<dim3(3,4),  256, 0, stream>>>(W1, wt1 + h*128*96, 78, 78, 96, 128, 312, h*78, flags);
  for (int h = 0; h < 4; ++h)
    transpose_pad<<<dim3(10,12), 256, 0, stream>>>(W2, wt2 + h*384*320, 312, 312, 320, 384, 1248, h*312, flags);
  transpose_pad<<<dim3(39,40), 256, 0, stream>>>(W3,   wt3, 1248, 1248, 1248, 1280, 1248, 0, flags);
  transpose_pad<<<dim3(39,32), 256, 0, stream>>>(fc1w, wf1, 1248, 1024, 1248, 1024, 1024, 0, flags);
  transpose_pad<<<dim3(32,4),  256, 0, stream>>>(fc2w, wf2, 1024, 128,  1024, 128,  128,  0, flags);
  copy_vec5<<<(312+1248+1248+1024+128+255)/256, 256, 0, stream>>>(
      b1, cb1, 312, b2, cb2, 1248, b3, cb3, 1248, fc1b, cbf1, 1024, fc2b, cbf2, 128, flags);
  copy_int3<<<(E+E+N+255)/256, 256, 0, stream>>>(ei, bat, rowC, colC, bat32, E, N, flags);
  wproj<<<dim3(1,4), 256, 0, stream>>>(W1, as1, ad1, ws1, wd1, 78, 80, 78, 312, flags);
  wproj<<<dim3(2,4), 256, 0, stream>>>(W2, as2, ad2, ws2, wd2, 312, 312, 312, 1248, flags);
  wproj<<<dim3(5,1), 256, 0, stream>>>(W3, as3, ad3, ws3, wd3, 1248, 1248, 1248, 1248, flags);

  // ---- CSR ----
  hist_kernel<<<(E+255)/256, 256, 0, stream>>>(colC, cnt, E);
  scan_local<<<nb1024, 1024, 0, stream>>>(cnt, rowptr, bsum, N);
  scan_bsums<<<1, 1024, 0, stream>>>(bsum, boff, nb1024);
  scan_fixup<<<nb1024, 1024, 0, stream>>>(rowptr, boff, N);
  fill_self<<<(N+255)/256, 256, 0, stream>>>(rowptr, eidx, cnt, N);
  fill_edges<<<(E+255)/256, 256, 0, stream>>>(rowC, colC, cnt, eidx, E);

  const int db = (N + 3)/4;

  // ---- conv1: x[N,96] -> xagg1[N,384] -> out1[N,312] in P (4 heads, 1 launch) ----
  attn_dots_v<4><<<db, 256, 0, stream>>>(xpad, 96, ws1, wd1, a_src, a_dst, N, 80);
  attn_stats<<<(N*4+255)/256, 256, 0, stream>>>(rowptr, eidx, a_src, a_dst, pbuf, invd, N*4, 4);
  aggregate_v<<<N, 64, 0, stream>>>(rowptr, eidx, pbuf, invd, xpad, 96, Q, 384, 10, 4, 96);
  gemm_bt<<<Mg8*4*1*8, 256, 0, stream>>>(Q, 384, wt1, cb1, P, N, 78, 96, 312, 1, flags,
                                         nullptr, nullptr, 0, 1, Mt, 4, 96, 128*96, 78);

  // ---- conv2: out1 -> xagg2[N,1248] -> out2[N,1248] in P (4 heads, 1 launch) ----
  attn_dots_v<4><<<db, 256, 0, stream>>>(P, 312, ws2, wd2, a_src, a_dst, N, 312);
  attn_stats<<<(N*4+255)/256, 256, 0, stream>>>(rowptr, eidx, a_src, a_dst, pbuf, invd, N*4, 4);
  aggregate_v<<<N, 192, 0, stream>>>(rowptr, eidx, pbuf, invd, P, 312, Q, 1248, 39, 4, 312);
  gemm_bt<<<Mg8*4*3*8, 256, 0, stream>>>(Q, 1248, wt2, cb2, P, N, 312, 320, 1248, 1, flags,
                                         nullptr, nullptr, 0, 3, Mt, 4, 312, 384*320, 312);

  // ---- conv3 (H=1): out2 -> xagg3 -> fused GEMM+pool ----
  attn_dots_v<1><<<db, 256, 0, stream>>>(P, 1248, ws3, wd3, a_src, a_dst, N, 1248);
  attn_stats<<<(N+255)/256, 256, 0, stream>>>(rowptr, eidx, a_src, a_dst, pbuf, invd, N, 1);
  aggregate_v<<<N, 192, 0, stream>>>(rowptr, eidx, pbuf, invd, P, 1248, Q, 1248, 156, 1, 0);
  gemm_bt<<<Mg8*10*8, 256, 0, stream>>>(Q, 1248, wt3, cb3, P, N, 1248, 1248, 1248, 1|4, flags,
                                        bat32, poolf, 1248, 10, Mt, 1, 0, 0, 0);

  // ---- pool pack + FCs ----
  pack_pool<<<(G*1248+255)/256, 256, 0, stream>>>(poolf, pooled, G*1248);
  gemm_bt<<<64, 256, 0, stream>>>(pooled, 1248, wf1, cbf1, fc1o, G, 1024, 1248, 1024, 1, flags,
                                  nullptr, nullptr, 0, 8, 4, 1, 0, 0, 0);
  gemm_bt<<<8, 256, 0, stream>>>(fc1o, 1024, wf2, cbf2, (u16*)d_out, G, 128, 1024, 128, 3, flags,
                                 nullptr, nullptr, 0, 1, 4, 1, 0, 0, 0);
}

// Round 9
// 1352.922 us; speedup vs baseline: 1.0536x; 1.0536x over previous
//
#include <hip/hip_runtime.h>

using u16 = unsigned short;
using u32 = unsigned int;

typedef short s16x8 __attribute__((ext_vector_type(8)));
typedef float f32x4 __attribute__((ext_vector_type(4)));

static __device__ __forceinline__ float b2f(u16 u){ u32 x = ((u32)u) << 16; float f; __builtin_memcpy(&f, &x, 4); return f; }
static __device__ __forceinline__ u16 f2bf(float f){ u32 x; __builtin_memcpy(&x, &f, 4); x += 0x7fffu + ((x >> 16) & 1u); return (u16)(x >> 16); }

static __device__ __forceinline__ void async16(const u16* g, u16* l){
  __builtin_amdgcn_global_load_lds((const __attribute__((address_space(1))) u32*)g,
                                   (__attribute__((address_space(3))) u32*)l, 16, 0, 0);
}

// ---------------------------------------------------------------------------
__global__ void detect_flags(const u16* x, const int* ei, int* flags){
  if (blockIdx.x || threadIdx.x) return;
  int cf = 0;
  for (int i = 0; i < 128; ++i){
    int ex = (x[2*i] >> 7) & 0xff;
    if (ex >= 110 && ex <= 140) cf++;
  }
  flags[0] = (cf > 64) ? 1 : 0;
  int cz = 0;
  for (int i = 0; i < 128; ++i){ if (ei[2*i+1] != 0) cz++; }
  flags[1] = (cz > 64) ? 1 : 0;
}

__global__ void zero_u32(u32* p, int n){
  int i = blockIdx.x*256 + threadIdx.x;
  if (i < n) p[i] = 0;
}

__global__ void pad_copy_x(const void* xin, u16* xp, int Nreal, long tot, int F, int Fp, const int* flags){
  long idx = (long)blockIdx.x*256 + threadIdx.x;
  if (idx >= tot) return;
  int n = (int)(idx / Fp), f = (int)(idx - (long)n*Fp);
  u16 v = 0;
  if (n < Nreal && f < F){
    if (flags[0]) v = ((const u16*)xin)[(long)n*F + f];
    else          v = f2bf(((const float*)xin)[(long)n*F + f]);
  }
  xp[idx] = v;
}

__global__ void transpose_pad(const void* W, u16* Wt, int K, int Nsub, int Kp, int Np,
                              int ldW, int colOff, const int* flags){
  __shared__ u16 tile[32][33];
  int f0 = flags[0];
  int kb = blockIdx.x*32, nb = blockIdx.y*32;
  int tx = threadIdx.x & 31, ty = threadIdx.x >> 5;
  for (int dy = 0; dy < 32; dy += 8){
    int k = kb + dy + ty, n = nb + tx;
    u16 v = 0;
    if (k < K && n < Nsub){
      long src = (long)k*ldW + colOff + n;
      if (f0) v = ((const u16*)W)[src];
      else    v = f2bf(((const float*)W)[src]);
    }
    tile[dy+ty][tx] = v;
  }
  __syncthreads();
  for (int dy = 0; dy < 32; dy += 8){
    int n = nb + dy + ty, k = kb + tx;
    if (n < Np && k < Kp) Wt[(long)n*Kp + k] = tile[tx][dy+ty];
  }
}

// five bias-style vectors in one launch
__global__ void copy_vec5(const void* s0, u16* d0, int n0,
                          const void* s1, u16* d1, int n1,
                          const void* s2, u16* d2, int n2,
                          const void* s3, u16* d3, int n3,
                          const void* s4, u16* d4, int n4,
                          const int* flags){
  int i = blockIdx.x*256 + threadIdx.x;
  int f0 = flags[0];
  auto cv = [&](const void* s, int j)->u16{
    return f0 ? ((const u16*)s)[j] : f2bf(((const float*)s)[j]);
  };
  if (i < n0){ d0[i] = cv(s0, i); return; } i -= n0;
  if (i < n1){ d1[i] = cv(s1, i); return; } i -= n1;
  if (i < n2){ d2[i] = cv(s2, i); return; } i -= n2;
  if (i < n3){ d3[i] = cv(s3, i); return; } i -= n3;
  if (i < n4){ d4[i] = cv(s4, i); }
}

// rowC/colC/bat32 in one launch
__global__ void copy_int3(const int* ei, const int* bat,
                          int* rowC, int* colC, int* bat32,
                          int E, int N, const int* flags){
  int i = blockIdx.x*256 + threadIdx.x;
  int f1 = flags[1];
  if (i < E){ rowC[i] = f1 ? ei[i] : ei[2*i]; return; } i -= E;
  if (i < E){ colC[i] = f1 ? ei[E + i] : ei[2*(E + i)]; return; } i -= E;
  if (i < N){ bat32[i] = f1 ? bat[i] : bat[2*i]; }
}

// ---------------------------------------------------------------------------
// CSR build
__global__ void hist_kernel(const int* __restrict__ colC, u32* cnt, int E){
  int e = blockIdx.x*256 + threadIdx.x;
  if (e < E) atomicAdd(&cnt[colC[e]], 1u);
}

__global__ void scan_local(const u32* __restrict__ cnt, u32* __restrict__ rowptr,
                           u32* __restrict__ bsum, int N){
  int blk = blockIdx.x, t = threadIdx.x;
  int i = blk*1024 + t;
  u32 v = (i < N) ? (cnt[i] + 1u) : 0u;
  u32 x = v;
  for (int off = 1; off < 64; off <<= 1){
    u32 y = __shfl_up(x, off);
    if ((t & 63) >= off) x += y;
  }
  __shared__ u32 ws[16];
  if ((t & 63) == 63) ws[t >> 6] = x;
  __syncthreads();
  if (t < 16){
    u32 y = ws[t];
    for (int off = 1; off < 16; off <<= 1){
      u32 z = __shfl_up(y, off);
      if (t >= off) y += z;
    }
    ws[t] = y;
  }
  __syncthreads();
  u32 base = (t >> 6) ? ws[(t >> 6) - 1] : 0u;
  u32 inc = base + x;
  if (i < N) rowptr[i + 1] = inc;
  if (t == 1023) bsum[blk] = inc;
}

__global__ void scan_bsums(const u32* __restrict__ bsum, u32* __restrict__ boff, int nb){
  int t = threadIdx.x;
  u32 v = (t < nb) ? bsum[t] : 0u;
  u32 x = v;
  for (int off = 1; off < 64; off <<= 1){
    u32 y = __shfl_up(x, off);
    if ((t & 63) >= off) x += y;
  }
  __shared__ u32 ws[16];
  if ((t & 63) == 63) ws[t >> 6] = x;
  __syncthreads();
  if (t < 16){
    u32 y = ws[t];
    for (int off = 1; off < 16; off <<= 1){
      u32 z = __shfl_up(y, off);
      if (t >= off) y += z;
    }
    ws[t] = y;
  }
  __syncthreads();
  u32 base = (t >> 6) ? ws[(t >> 6) - 1] : 0u;
  u32 inc = base + x;
  if (t < nb) boff[t] = inc - v;
}

__global__ void scan_fixup(u32* rowptr, const u32* __restrict__ boff, int N){
  int i = blockIdx.x*1024 + threadIdx.x;
  if (i < N) rowptr[i+1] += boff[blockIdx.x];
  if (i == 0) rowptr[0] = 0;
}

__global__ void fill_self(const u32* rowptr, int* eidx, u32* cursor, int N){
  int i = blockIdx.x*256 + threadIdx.x;
  if (i >= N) return;
  eidx[rowptr[i]] = i;
  cursor[i] = rowptr[i] + 1;
}

__global__ void fill_edges(const int* __restrict__ rowC, const int* __restrict__ colC,
                           u32* cursor, int* eidx, int E){
  int e = blockIdx.x*256 + threadIdx.x;
  if (e >= E) return;
  u32 pos = atomicAdd(&cursor[colC[e]], 1u);
  eidx[pos] = rowC[e];
}

// ---------------------------------------------------------------------------
__global__ void wproj(const void* W, const void* as, const void* ad,
                      float* wsrc, float* wdst, int Cin, int Cpad, int Chead, int ldW,
                      const int* flags){
  int h = blockIdx.y;
  int c = blockIdx.x*256 + threadIdx.x;
  if (c >= Cpad) return;
  int f0 = flags[0];
  float s = 0.f, d = 0.f;
  if (c < Cin){
    long base = (long)c*ldW + (long)h*Chead;
    for (int o = 0; o < Chead; ++o){
      float wv = f0 ? b2f(((const u16*)W)[base+o]) : ((const float*)W)[base+o];
      float av = f0 ? b2f(((const u16*)as)[h*Chead+o]) : ((const float*)as)[h*Chead+o];
      float dv = f0 ? b2f(((const u16*)ad)[h*Chead+o]) : ((const float*)ad)[h*Chead+o];
      s += wv*av; d += wv*dv;
    }
  }
  wsrc[h*Cpad+c] = s; wdst[h*Cpad+c] = d;
}

template<int H>
__global__ void attn_dots_v(const u16* __restrict__ xin, long ldx,
                            const float* __restrict__ wsrc, const float* __restrict__ wdst,
                            float* __restrict__ a_src, float* __restrict__ a_dst,
                            int Nn, int C){
  int node = blockIdx.x*4 + (threadIdx.x >> 6);
  if (node >= Nn) return;
  int lane = threadIdx.x & 63;
  const u16* xr = xin + (long)node*ldx;
  float s[H], d[H];
#pragma unroll
  for (int h = 0; h < H; ++h){ s[h] = 0.f; d[h] = 0.f; }
  for (int c = lane*8; c < C; c += 512){
    s16x8 xv = *(const s16x8*)&xr[c];
    float xf[8];
#pragma unroll
    for (int j = 0; j < 8; ++j) xf[j] = b2f((u16)xv[j]);
#pragma unroll
    for (int h = 0; h < H; ++h){
      f32x4 w0 = *(const f32x4*)&wsrc[h*C + c];
      f32x4 w1 = *(const f32x4*)&wsrc[h*C + c + 4];
      f32x4 d0 = *(const f32x4*)&wdst[h*C + c];
      f32x4 d1 = *(const f32x4*)&wdst[h*C + c + 4];
#pragma unroll
      for (int j = 0; j < 4; ++j){
        s[h] += xf[j]*w0[j] + xf[j+4]*w1[j];
        d[h] += xf[j]*d0[j] + xf[j+4]*d1[j];
      }
    }
  }
#pragma unroll
  for (int h = 0; h < H; ++h)
    for (int off = 32; off; off >>= 1){ s[h] += __shfl_down(s[h], off); d[h] += __shfl_down(d[h], off); }
  if (lane == 0){
#pragma unroll
    for (int h = 0; h < H; ++h){ a_src[(long)node*H+h] = s[h]; a_dst[(long)node*H+h] = d[h]; }
  }
}

__global__ void attn_stats(const u32* __restrict__ rowptr, const int* __restrict__ eidx,
                           const float* __restrict__ a_src, const float* __restrict__ a_dst,
                           u16* __restrict__ pbuf, float* __restrict__ invd, int NH, int H){
  int idx = blockIdx.x*256 + threadIdx.x;
  if (idx >= NH) return;
  int i = idx / H, hd = idx - i*H;
  u32 s0 = rowptr[i], s1 = rowptr[i+1];
  float ad = a_dst[idx];
  float m = -1e30f;
  for (u32 p = s0; p < s1; ++p){
    float e = a_src[eidx[p]*H + hd] + ad;
    e = e > 0.f ? e : 0.2f*e;
    m = fmaxf(m, e);
  }
  float den = 0.f;
  for (u32 p = s0; p < s1; ++p){
    float e = a_src[eidx[p]*H + hd] + ad;
    e = e > 0.f ? e : 0.2f*e;
    float v = __expf(e - m);
    pbuf[(long)p*H + hd] = f2bf(v);
    den += v;
  }
  invd[idx] = 1.f / (den + 1e-16f);
}

__global__ void aggregate_v(const u32* __restrict__ rowptr, const int* __restrict__ eidx,
                            const u16* __restrict__ pbuf, const float* __restrict__ invd,
                            const u16* __restrict__ xin, long ldx,
                            u16* __restrict__ xagg, long ldagg,
                            int chunks, int H, int headStride){
  int i = blockIdx.x;
  int t = threadIdx.x;
  if (t >= H*chunks) return;
  int h = t / chunks, ck = t - h*chunks;
  int c0 = ck*8;
  u32 s0 = rowptr[i], s1 = rowptr[i+1];
  float acc[8];
#pragma unroll
  for (int j = 0; j < 8; ++j) acc[j] = 0.f;
  int src = eidx[s0];
  for (u32 p = s0; p < s1; ++p){
    int nsrc = (p+1 < s1) ? eidx[p+1] : 0;
    float wgt = b2f(pbuf[(long)p*H + h]);
    s16x8 v = *(const s16x8*)&xin[(long)src*ldx + c0];
#pragma unroll
    for (int j = 0; j < 8; ++j) acc[j] += wgt * b2f((u16)v[j]);
    src = nsrc;
  }
  float inv = invd[(long)i*H + h];
  s16x8 ov;
#pragma unroll
  for (int j = 0; j < 8; ++j) ov[j] = (short)f2bf(acc[j]*inv);
  *(s16x8*)&xagg[(long)i*ldagg + h*headStride + c0] = ov;
}

__global__ void pack_pool(const u32* __restrict__ poolf, u16* __restrict__ pooled, int n){
  int i = blockIdx.x*256 + threadIdx.x;
  if (i >= n) return;
  u32 b = poolf[i]; float f; __builtin_memcpy(&f, &b, 4);
  pooled[i] = f2bf(f);
}

// ---------------------------------------------------------------------------
// Multi-head batched GEMM (NH compile-time): head h computes
// C_h[M,Nstore] = A_h[M,K](lda) @ B_h[*,K]^T with A_h=Ag+h*hA, B_h=Bg+h*hB,
// bias_h/C_h offset h*hC. NH=1 folds all head math away (VGPR 84 -> 6 blocks/CU,
// the R6-verified occupancy point; NH=4 at 88 VGPR is fine for the small layers).
// 1D grid, XCD-aware decode. BK=32. K mult of 32 (B K-pad rows zeroed).
// mode bit0: bias+relu; bit1: store dtype per flags[0]; bit2: fused graph-max-pool.
template<int NH>
__global__ __launch_bounds__(256) void gemm_bt(
    const u16* __restrict__ Ag, long lda, const u16* __restrict__ Bg,
    const u16* __restrict__ bias, u16* __restrict__ Cg,
    int M, int Nstore, int K, long ldc, int mode, const int* flags,
    const int* __restrict__ batg, u32* poolf, long ldp,
    int nt, int mt, long hA, long hB, long hC)
{
  const int xcd = blockIdx.x & 7;
  const int g = blockIdx.x >> 3;
  const u16 *A, *B, *bi; u16* C;
  int ntile, m;
  if constexpr (NH > 1){
    const int nhnt = NH * nt;
    const int inner = g % nhnt;
    ntile = inner % nt;
    const int head = inner / nt;
    m = (g / nhnt)*8 + xcd;
    A = Ag + (long)head*hA; B = Bg + (long)head*hB;
    bi = bias + (long)head*hC; C = Cg + (long)head*hC;
  } else {
    ntile = g % nt;
    m = (g / nt)*8 + xcd;
    A = Ag; B = Bg; bi = bias; C = Cg;
  }
  if (m >= mt) return;

  __shared__ __align__(16) u16 As[128*32];
  __shared__ __align__(16) u16 Bs[128*32];
  const int tid = threadIdx.x;
  const int wave = tid >> 6, lane = tid & 63;
  const int quad = lane >> 4, mrow = lane & 15;
  const int wm = (wave >> 1) * 64, wn = (wave & 1) * 64;
  const long bm = (long)m * 128;
  const long bn = (long)ntile * 128;

  f32x4 acc[4][4];
#pragma unroll
  for (int i = 0; i < 4; i++)
#pragma unroll
    for (int j = 0; j < 4; j++) acc[i][j] = (f32x4){0.f, 0.f, 0.f, 0.f};

  const int r0 = wave*32 + (lane >> 2);
  const int r1 = r0 + 16;
  const int kcl = lane & 3;
  const int q0 = kcl ^ ((r0 >> 1) & 3);
  const int q1 = kcl ^ ((r1 >> 1) & 3);
  const u16* a0 = A + (bm + r0)*lda + q0*8;
  const u16* a1 = A + (bm + r1)*lda + q1*8;
  const u16* b0 = B + (bn + r0)*(long)K + q0*8;
  const u16* b1 = B + (bn + r1)*(long)K + q1*8;
  u16* la0 = &As[r0*32 + kcl*8];
  u16* la1 = &As[r1*32 + kcl*8];
  u16* lb0 = &Bs[r0*32 + kcl*8];
  u16* lb1 = &Bs[r1*32 + kcl*8];

  for (int k0 = 0; k0 < K; k0 += 32){
    async16(a0 + k0, la0);
    async16(a1 + k0, la1);
    async16(b0 + k0, lb0);
    async16(b1 + k0, lb1);
    __syncthreads();
    s16x8 af[4], bf[4];
#pragma unroll
    for (int i = 0; i < 4; i++){
      int r = wm + i*16 + mrow;
      int q = quad ^ ((r >> 1) & 3);
      af[i] = *(const s16x8*)&As[r*32 + q*8];
    }
#pragma unroll
    for (int j = 0; j < 4; j++){
      int r = wn + j*16 + mrow;
      int q = quad ^ ((r >> 1) & 3);
      bf[j] = *(const s16x8*)&Bs[r*32 + q*8];
    }
#pragma unroll
    for (int i = 0; i < 4; i++)
#pragma unroll
      for (int j = 0; j < 4; j++)
        acc[i][j] = __builtin_amdgcn_mfma_f32_16x16x32_bf16(af[i], bf[j], acc[i][j], 0, 0, 0);
    __syncthreads();
  }

  if (mode & 4){
    int garr[16];
#pragma unroll
    for (int i = 0; i < 4; i++)
#pragma unroll
      for (int r = 0; r < 4; r++){
        long row = bm + wm + i*16 + quad*4 + r;
        garr[i*4+r] = (row < M) ? batg[row] : -1;
      }
#pragma unroll
    for (int j = 0; j < 4; j++){
      long col = bn + wn + j*16 + mrow;
      if (col >= Nstore) continue;
      float bv = b2f(bi[col]);
      int curg = -1; float curm = 0.f;
#pragma unroll
      for (int i = 0; i < 4; i++)
#pragma unroll
        for (int r = 0; r < 4; r++){
          int g2 = garr[i*4+r];
          if (g2 >= 0){
            float v = fmaxf(acc[i][j][r] + bv, 0.f);
            if (g2 != curg){
              if (curg >= 0){
                u32 bits; __builtin_memcpy(&bits, &curm, 4);
                atomicMax(&poolf[(long)curg*ldp + col], bits);
              }
              curg = g2; curm = v;
            } else curm = fmaxf(curm, v);
          }
        }
      if (curg >= 0){
        u32 bits; __builtin_memcpy(&bits, &curm, 4);
        atomicMax(&poolf[(long)curg*ldp + col], bits);
      }
    }
    return;
  }

  const int f0 = (mode & 2) ? flags[0] : 1;
#pragma unroll
  for (int i = 0; i < 4; i++){
    long row0 = bm + wm + i*16 + quad*4;
#pragma unroll
    for (int j = 0; j < 4; j++){
      long col = bn + wn + j*16 + mrow;
      if (col < Nstore){
        float bv = (mode & 1) ? b2f(bi[col]) : 0.f;
#pragma unroll
        for (int r = 0; r < 4; r++){
          long row = row0 + r;
          if (row < M){
            float v = acc[i][j][r];
            if (mode & 1) v = fmaxf(v + bv, 0.f);
            if (f0) C[row*ldc + col] = f2bf(v);
            else    ((float*)C)[row*ldc + col] = v;
          }
        }
      }
    }
  }
}

// ---------------------------------------------------------------------------
extern "C" void kernel_launch(void* const* d_in, const int* in_sizes, int n_in,
                              void* d_out, int out_size, void* d_ws, size_t ws_size,
                              hipStream_t stream){
  const u16* x    = (const u16*)d_in[0];
  const int* ei   = (const int*)d_in[1];
  const int* bat  = (const int*)d_in[2];
  const void* W1  = d_in[3];
  const void* as1 = d_in[4]; const void* ad1 = d_in[5]; const void* b1 = d_in[6];
  const void* W2  = d_in[7];
  const void* as2 = d_in[8]; const void* ad2 = d_in[9]; const void* b2 = d_in[10];
  const void* W3  = d_in[11];
  const void* as3 = d_in[12]; const void* ad3 = d_in[13]; const void* b3 = d_in[14];
  const void* fc1w = d_in[15]; const void* fc1b = d_in[16];
  const void* fc2w = d_in[17]; const void* fc2b = d_in[18];

  const int E = in_sizes[1] / 2;
  const int N = in_sizes[2];
  const int G = 512, H = 4;
  const int Mpad = ((N + 127)/128)*128;
  const int Etot = E + N;
  const int Mt = Mpad/128;                 // 391
  const int nb1024 = (N + 1023)/1024;
  const int Mg8 = ((Mt + 7)/8);            // 49 M-groups of 8

  char* w = (char*)d_ws;
  size_t off = 0;
  auto AL = [&](size_t b)->char*{ char* p = w + off; off = (off + b + 255) & ~(size_t)255; return p; };

  u16* P = (u16*)AL((size_t)Mpad*1248*2 + 512);
  u16* Q = (u16*)AL((size_t)Mpad*1248*2 + 512);
  u16* wt1 = (u16*)AL((size_t)4*128*96*2);
  u16* wt2 = (u16*)AL((size_t)4*384*320*2);
  u16* wt3 = (u16*)AL((size_t)1280*1248*2);
  u16* wf1 = (u16*)AL((size_t)1024*1248*2);
  u16* wf2 = (u16*)AL((size_t)128*1024*2);
  u16* cb1 = (u16*)AL(312*2);  u16* cb2 = (u16*)AL(1248*2); u16* cb3 = (u16*)AL(1248*2);
  u16* cbf1 = (u16*)AL(1024*2); u16* cbf2 = (u16*)AL(128*2);
  float* ws1 = (float*)AL(4*80*4);   float* wd1 = (float*)AL(4*80*4);
  float* ws2 = (float*)AL(4*312*4);  float* wd2 = (float*)AL(4*312*4);
  float* ws3 = (float*)AL(1248*4);   float* wd3 = (float*)AL(1248*4);
  float* a_src = (float*)AL((size_t)N*H*4);
  float* a_dst = (float*)AL((size_t)N*H*4);
  float* invd  = (float*)AL((size_t)N*H*4);
  u16*  pbuf   = (u16*)AL((size_t)Etot*H*2);
  u32* cnt     = (u32*)AL((size_t)N*4);
  u32* rowptr  = (u32*)AL((size_t)(N+1)*4);
  u32* bsum    = (u32*)AL((size_t)1024*4);
  u32* boff    = (u32*)AL((size_t)1024*4);
  int* eidx    = (int*)AL((size_t)Etot*4);
  int* bat32   = (int*)AL((size_t)N*4);
  u32* poolf   = (u32*)AL((size_t)G*1248*4);
  u16* pooled  = (u16*)AL((size_t)G*1248*2 + 512);
  u16* fc1o    = (u16*)AL((size_t)G*1024*2 + 512);
  int* flags   = (int*)AL(16);

  if (ws_size < off || n_in < 19) return;

  u16* xpad = (u16*)((char*)P + ((size_t)40 << 20));
  int* rowC = (int*)((char*)Q + ((size_t)64 << 20));
  int* colC = rowC + E;

  // ---- ingest ----
  detect_flags<<<1, 64, 0, stream>>>(x, ei, flags);
  zero_u32<<<(N+255)/256, 256, 0, stream>>>(cnt, N);
  zero_u32<<<(G*1248+255)/256, 256, 0, stream>>>(poolf, G*1248);
  {
    long tot = (long)Mpad*96;
    pad_copy_x<<<(unsigned)((tot+255)/256), 256, 0, stream>>>(x, xpad, N, tot, 78, 96, flags);
  }
  for (int h = 0; h < 4; ++h)
    transpose_pad<<<dim3(3,4),  256, 0, stream>>>(W1, wt1 + h*128*96, 78, 78, 96, 128, 312, h*78, flags);
  for (int h = 0; h < 4; ++h)
    transpose_pad<<<dim3(10,12), 256, 0, stream>>>(W2, wt2 + h*384*320, 312, 312, 320, 384, 1248, h*312, flags);
  transpose_pad<<<dim3(39,40), 256, 0, stream>>>(W3,   wt3, 1248, 1248, 1248, 1280, 1248, 0, flags);
  transpose_pad<<<dim3(39,32), 256, 0, stream>>>(fc1w, wf1, 1248, 1024, 1248, 1024, 1024, 0, flags);
  transpose_pad<<<dim3(32,4),  256, 0, stream>>>(fc2w, wf2, 1024, 128,  1024, 128,  128,  0, flags);
  copy_vec5<<<(312+1248+1248+1024+128+255)/256, 256, 0, stream>>>(
      b1, cb1, 312, b2, cb2, 1248, b3, cb3, 1248, fc1b, cbf1, 1024, fc2b, cbf2, 128, flags);
  copy_int3<<<(E+E+N+255)/256, 256, 0, stream>>>(ei, bat, rowC, colC, bat32, E, N, flags);
  wproj<<<dim3(1,4), 256, 0, stream>>>(W1, as1, ad1, ws1, wd1, 78, 80, 78, 312, flags);
  wproj<<<dim3(2,4), 256, 0, stream>>>(W2, as2, ad2, ws2, wd2, 312, 312, 312, 1248, flags);
  wproj<<<dim3(5,1), 256, 0, stream>>>(W3, as3, ad3, ws3, wd3, 1248, 1248, 1248, 1248, flags);

  // ---- CSR ----
  hist_kernel<<<(E+255)/256, 256, 0, stream>>>(colC, cnt, E);
  scan_local<<<nb1024, 1024, 0, stream>>>(cnt, rowptr, bsum, N);
  scan_bsums<<<1, 1024, 0, stream>>>(bsum, boff, nb1024);
  scan_fixup<<<nb1024, 1024, 0, stream>>>(rowptr, boff, N);
  fill_self<<<(N+255)/256, 256, 0, stream>>>(rowptr, eidx, cnt, N);
  fill_edges<<<(E+255)/256, 256, 0, stream>>>(rowC, colC, cnt, eidx, E);

  const int db = (N + 3)/4;

  // ---- conv1: x[N,96] -> xagg1[N,384] -> out1[N,312] in P (4 heads, 1 launch) ----
  attn_dots_v<4><<<db, 256, 0, stream>>>(xpad, 96, ws1, wd1, a_src, a_dst, N, 80);
  attn_stats<<<(N*4+255)/256, 256, 0, stream>>>(rowptr, eidx, a_src, a_dst, pbuf, invd, N*4, 4);
  aggregate_v<<<N, 64, 0, stream>>>(rowptr, eidx, pbuf, invd, xpad, 96, Q, 384, 10, 4, 96);
  gemm_bt<4><<<Mg8*4*1*8, 256, 0, stream>>>(Q, 384, wt1, cb1, P, N, 78, 96, 312, 1, flags,
                                            nullptr, nullptr, 0, 1, Mt, 96, 128*96, 78);

  // ---- conv2: out1 -> xagg2[N,1248] -> out2[N,1248] in P (4 heads, 1 launch) ----
  attn_dots_v<4><<<db, 256, 0, stream>>>(P, 312, ws2, wd2, a_src, a_dst, N, 312);
  attn_stats<<<(N*4+255)/256, 256, 0, stream>>>(rowptr, eidx, a_src, a_dst, pbuf, invd, N*4, 4);
  aggregate_v<<<N, 192, 0, stream>>>(rowptr, eidx, pbuf, invd, P, 312, Q, 1248, 39, 4, 312);
  gemm_bt<4><<<Mg8*4*3*8, 256, 0, stream>>>(Q, 1248, wt2, cb2, P, N, 312, 320, 1248, 1, flags,
                                            nullptr, nullptr, 0, 3, Mt, 312, 384*320, 312);

  // ---- conv3 (H=1): out2 -> xagg3 -> fused GEMM+pool (NH=1: lean 84-VGPR path) ----
  attn_dots_v<1><<<db, 256, 0, stream>>>(P, 1248, ws3, wd3, a_src, a_dst, N, 1248);
  attn_stats<<<(N+255)/256, 256, 0, stream>>>(rowptr, eidx, a_src, a_dst, pbuf, invd, N, 1);
  aggregate_v<<<N, 192, 0, stream>>>(rowptr, eidx, pbuf, invd, P, 1248, Q, 1248, 156, 1, 0);
  gemm_bt<1><<<Mg8*10*8, 256, 0, stream>>>(Q, 1248, wt3, cb3, P, N, 1248, 1248, 1248, 1|4, flags,
                                           bat32, poolf, 1248, 10, Mt, 0, 0, 0);

  // ---- pool pack + FCs ----
  pack_pool<<<(G*1248+255)/256, 256, 0, stream>>>(poolf, pooled, G*1248);
  gemm_bt<1><<<64, 256, 0, stream>>>(pooled, 1248, wf1, cbf1, fc1o, G, 1024, 1248, 1024, 1, flags,
                                     nullptr, nullptr, 0, 8, 4, 0, 0, 0);
  gemm_bt<1><<<8, 256, 0, stream>>>(fc1o, 1024, wf2, cbf2, (u16*)d_out, G, 128, 1024, 128, 3, flags,
                                    nullptr, nullptr, 0, 1, 4, 0, 0, 0);
}

// Round 10
// 1064.317 us; speedup vs baseline: 1.3393x; 1.2712x over previous
//
#include <hip/hip_runtime.h>

using u16 = unsigned short;
using u32 = unsigned int;

typedef short s16x8 __attribute__((ext_vector_type(8)));
typedef float f32x4 __attribute__((ext_vector_type(4)));

static __device__ __forceinline__ float b2f(u16 u){ u32 x = ((u32)u) << 16; float f; __builtin_memcpy(&f, &x, 4); return f; }
static __device__ __forceinline__ u16 f2bf(float f){ u32 x; __builtin_memcpy(&x, &f, 4); x += 0x7fffu + ((x >> 16) & 1u); return (u16)(x >> 16); }

static __device__ __forceinline__ void async16(const u16* g, u16* l){
  __builtin_amdgcn_global_load_lds((const __attribute__((address_space(1))) u32*)g,
                                   (__attribute__((address_space(3))) u32*)l, 16, 0, 0);
}

// ---------------------------------------------------------------------------
__global__ void detect_flags(const u16* x, const int* ei, int* flags){
  if (blockIdx.x || threadIdx.x) return;
  int cf = 0;
  for (int i = 0; i < 128; ++i){
    int ex = (x[2*i] >> 7) & 0xff;
    if (ex >= 110 && ex <= 140) cf++;
  }
  flags[0] = (cf > 64) ? 1 : 0;
  int cz = 0;
  for (int i = 0; i < 128; ++i){ if (ei[2*i+1] != 0) cz++; }
  flags[1] = (cz > 64) ? 1 : 0;
}

__global__ void zero_u32(u32* p, int n){
  int i = blockIdx.x*256 + threadIdx.x;
  if (i < n) p[i] = 0;
}

__global__ void pad_copy_x(const void* xin, u16* xp, int Nreal, long tot, int F, int Fp, const int* flags){
  long idx = (long)blockIdx.x*256 + threadIdx.x;
  if (idx >= tot) return;
  int n = (int)(idx / Fp), f = (int)(idx - (long)n*Fp);
  u16 v = 0;
  if (n < Nreal && f < F){
    if (flags[0]) v = ((const u16*)xin)[(long)n*F + f];
    else          v = f2bf(((const float*)xin)[(long)n*F + f]);
  }
  xp[idx] = v;
}

__global__ void transpose_pad(const void* W, u16* Wt, int K, int Nsub, int Kp, int Np,
                              int ldW, int colOff, const int* flags){
  __shared__ u16 tile[32][33];
  int f0 = flags[0];
  int kb = blockIdx.x*32, nb = blockIdx.y*32;
  int tx = threadIdx.x & 31, ty = threadIdx.x >> 5;
  for (int dy = 0; dy < 32; dy += 8){
    int k = kb + dy + ty, n = nb + tx;
    u16 v = 0;
    if (k < K && n < Nsub){
      long src = (long)k*ldW + colOff + n;
      if (f0) v = ((const u16*)W)[src];
      else    v = f2bf(((const float*)W)[src]);
    }
    tile[dy+ty][tx] = v;
  }
  __syncthreads();
  for (int dy = 0; dy < 32; dy += 8){
    int n = nb + dy + ty, k = kb + tx;
    if (n < Np && k < Kp) Wt[(long)n*Kp + k] = tile[tx][dy+ty];
  }
}

// five bias-style vectors in one launch
__global__ void copy_vec5(const void* s0, u16* d0, int n0,
                          const void* s1, u16* d1, int n1,
                          const void* s2, u16* d2, int n2,
                          const void* s3, u16* d3, int n3,
                          const void* s4, u16* d4, int n4,
                          const int* flags){
  int i = blockIdx.x*256 + threadIdx.x;
  int f0 = flags[0];
  auto cv = [&](const void* s, int j)->u16{
    return f0 ? ((const u16*)s)[j] : f2bf(((const float*)s)[j]);
  };
  if (i < n0){ d0[i] = cv(s0, i); return; } i -= n0;
  if (i < n1){ d1[i] = cv(s1, i); return; } i -= n1;
  if (i < n2){ d2[i] = cv(s2, i); return; } i -= n2;
  if (i < n3){ d3[i] = cv(s3, i); return; } i -= n3;
  if (i < n4){ d4[i] = cv(s4, i); }
}

// rowC/colC/bat32 in one launch
__global__ void copy_int3(const int* ei, const int* bat,
                          int* rowC, int* colC, int* bat32,
                          int E, int N, const int* flags){
  int i = blockIdx.x*256 + threadIdx.x;
  int f1 = flags[1];
  if (i < E){ rowC[i] = f1 ? ei[i] : ei[2*i]; return; } i -= E;
  if (i < E){ colC[i] = f1 ? ei[E + i] : ei[2*(E + i)]; return; } i -= E;
  if (i < N){ bat32[i] = f1 ? bat[i] : bat[2*i]; }
}

// ---------------------------------------------------------------------------
// CSR build
__global__ void hist_kernel(const int* __restrict__ colC, u32* cnt, int E){
  int e = blockIdx.x*256 + threadIdx.x;
  if (e < E) atomicAdd(&cnt[colC[e]], 1u);
}

__global__ void scan_local(const u32* __restrict__ cnt, u32* __restrict__ rowptr,
                           u32* __restrict__ bsum, int N){
  int blk = blockIdx.x, t = threadIdx.x;
  int i = blk*1024 + t;
  u32 v = (i < N) ? (cnt[i] + 1u) : 0u;
  u32 x = v;
  for (int off = 1; off < 64; off <<= 1){
    u32 y = __shfl_up(x, off);
    if ((t & 63) >= off) x += y;
  }
  __shared__ u32 ws[16];
  if ((t & 63) == 63) ws[t >> 6] = x;
  __syncthreads();
  if (t < 16){
    u32 y = ws[t];
    for (int off = 1; off < 16; off <<= 1){
      u32 z = __shfl_up(y, off);
      if (t >= off) y += z;
    }
    ws[t] = y;
  }
  __syncthreads();
  u32 base = (t >> 6) ? ws[(t >> 6) - 1] : 0u;
  u32 inc = base + x;
  if (i < N) rowptr[i + 1] = inc;
  if (t == 1023) bsum[blk] = inc;
}

__global__ void scan_bsums(const u32* __restrict__ bsum, u32* __restrict__ boff, int nb){
  int t = threadIdx.x;
  u32 v = (t < nb) ? bsum[t] : 0u;
  u32 x = v;
  for (int off = 1; off < 64; off <<= 1){
    u32 y = __shfl_up(x, off);
    if ((t & 63) >= off) x += y;
  }
  __shared__ u32 ws[16];
  if ((t & 63) == 63) ws[t >> 6] = x;
  __syncthreads();
  if (t < 16){
    u32 y = ws[t];
    for (int off = 1; off < 16; off <<= 1){
      u32 z = __shfl_up(y, off);
      if (t >= off) y += z;
    }
    ws[t] = y;
  }
  __syncthreads();
  u32 base = (t >> 6) ? ws[(t >> 6) - 1] : 0u;
  u32 inc = base + x;
  if (t < nb) boff[t] = inc - v;
}

__global__ void scan_fixup(u32* rowptr, const u32* __restrict__ boff, int N){
  int i = blockIdx.x*1024 + threadIdx.x;
  if (i < N) rowptr[i+1] += boff[blockIdx.x];
  if (i == 0) rowptr[0] = 0;
}

__global__ void fill_self(const u32* rowptr, int* eidx, u32* cursor, int N){
  int i = blockIdx.x*256 + threadIdx.x;
  if (i >= N) return;
  eidx[rowptr[i]] = i;
  cursor[i] = rowptr[i] + 1;
}

__global__ void fill_edges(const int* __restrict__ rowC, const int* __restrict__ colC,
                           u32* cursor, int* eidx, int E){
  int e = blockIdx.x*256 + threadIdx.x;
  if (e >= E) return;
  u32 pos = atomicAdd(&cursor[colC[e]], 1u);
  eidx[pos] = rowC[e];
}

// ---------------------------------------------------------------------------
// wsrc[h*Cpad+c] = sum_o W[c*ldW + h*Chead + o]*as[h*Chead+o]
// One WAVE per (head, col): lanes sweep the contiguous W row (coalesced 128B),
// shuffle reduce. (Old version: 1 thread/col with a 1248-iter strided loop on a
// 5-block grid — a latency-serial straggler.)
__global__ void wproj(const void* W, const void* as, const void* ad,
                      float* wsrc, float* wdst, int Cin, int Cpad, int Chead, int ldW,
                      int H, const int* flags){
  int wid = blockIdx.x*4 + (threadIdx.x >> 6);
  if (wid >= H*Cpad) return;
  int h = wid / Cpad, c = wid - h*Cpad;
  int lane = threadIdx.x & 63;
  float s = 0.f, d = 0.f;
  if (c < Cin){
    int f0 = flags[0];
    long base = (long)c*ldW + (long)h*Chead;
    const long av0 = (long)h*Chead;
    for (int o = lane; o < Chead; o += 64){
      float wv = f0 ? b2f(((const u16*)W)[base+o]) : ((const float*)W)[base+o];
      float avv = f0 ? b2f(((const u16*)as)[av0+o]) : ((const float*)as)[av0+o];
      float dvv = f0 ? b2f(((const u16*)ad)[av0+o]) : ((const float*)ad)[av0+o];
      s += wv*avv; d += wv*dvv;
    }
    for (int off = 32; off; off >>= 1){ s += __shfl_down(s, off); d += __shfl_down(d, off); }
  }
  if (lane == 0){ wsrc[(long)h*Cpad+c] = s; wdst[(long)h*Cpad+c] = d; }
}

template<int H>
__global__ void attn_dots_v(const u16* __restrict__ xin, long ldx,
                            const float* __restrict__ wsrc, const float* __restrict__ wdst,
                            float* __restrict__ a_src, float* __restrict__ a_dst,
                            int Nn, int C){
  int node = blockIdx.x*4 + (threadIdx.x >> 6);
  if (node >= Nn) return;
  int lane = threadIdx.x & 63;
  const u16* xr = xin + (long)node*ldx;
  float s[H], d[H];
#pragma unroll
  for (int h = 0; h < H; ++h){ s[h] = 0.f; d[h] = 0.f; }
  for (int c = lane*8; c < C; c += 512){
    s16x8 xv = *(const s16x8*)&xr[c];
    float xf[8];
#pragma unroll
    for (int j = 0; j < 8; ++j) xf[j] = b2f((u16)xv[j]);
#pragma unroll
    for (int h = 0; h < H; ++h){
      f32x4 w0 = *(const f32x4*)&wsrc[h*C + c];
      f32x4 w1 = *(const f32x4*)&wsrc[h*C + c + 4];
      f32x4 d0 = *(const f32x4*)&wdst[h*C + c];
      f32x4 d1 = *(const f32x4*)&wdst[h*C + c + 4];
#pragma unroll
      for (int j = 0; j < 4; ++j){
        s[h] += xf[j]*w0[j] + xf[j+4]*w1[j];
        d[h] += xf[j]*d0[j] + xf[j+4]*d1[j];
      }
    }
  }
#pragma unroll
  for (int h = 0; h < H; ++h)
    for (int off = 32; off; off >>= 1){ s[h] += __shfl_down(s[h], off); d[h] += __shfl_down(d[h], off); }
  if (lane == 0){
#pragma unroll
    for (int h = 0; h < H; ++h){ a_src[(long)node*H+h] = s[h]; a_dst[(long)node*H+h] = d[h]; }
  }
}

__global__ void attn_stats(const u32* __restrict__ rowptr, const int* __restrict__ eidx,
                           const float* __restrict__ a_src, const float* __restrict__ a_dst,
                           u16* __restrict__ pbuf, float* __restrict__ invd, int NH, int H){
  int idx = blockIdx.x*256 + threadIdx.x;
  if (idx >= NH) return;
  int i = idx / H, hd = idx - i*H;
  u32 s0 = rowptr[i], s1 = rowptr[i+1];
  float ad = a_dst[idx];
  float m = -1e30f;
  for (u32 p = s0; p < s1; ++p){
    float e = a_src[eidx[p]*H + hd] + ad;
    e = e > 0.f ? e : 0.2f*e;
    m = fmaxf(m, e);
  }
  float den = 0.f;
  for (u32 p = s0; p < s1; ++p){
    float e = a_src[eidx[p]*H + hd] + ad;
    e = e > 0.f ? e : 0.2f*e;
    float v = __expf(e - m);
    pbuf[(long)p*H + hd] = f2bf(v);
    den += v;
  }
  invd[idx] = 1.f / (den + 1e-16f);
}

// edge loop unrolled x2: two gathers in flight per iteration
__global__ void aggregate_v(const u32* __restrict__ rowptr, const int* __restrict__ eidx,
                            const u16* __restrict__ pbuf, const float* __restrict__ invd,
                            const u16* __restrict__ xin, long ldx,
                            u16* __restrict__ xagg, long ldagg,
                            int chunks, int H, int headStride){
  int i = blockIdx.x;
  int t = threadIdx.x;
  if (t >= H*chunks) return;
  int h = t / chunks, ck = t - h*chunks;
  int c0 = ck*8;
  u32 s0 = rowptr[i], s1 = rowptr[i+1];
  float acc[8];
#pragma unroll
  for (int j = 0; j < 8; ++j) acc[j] = 0.f;
  u32 p = s0;
  for (; p + 2 <= s1; p += 2){
    int sa = eidx[p], sb = eidx[p+1];
    float wa = b2f(pbuf[(long)p*H + h]);
    float wb = b2f(pbuf[(long)(p+1)*H + h]);
    s16x8 va = *(const s16x8*)&xin[(long)sa*ldx + c0];
    s16x8 vb = *(const s16x8*)&xin[(long)sb*ldx + c0];
#pragma unroll
    for (int j = 0; j < 8; ++j) acc[j] += wa*b2f((u16)va[j]) + wb*b2f((u16)vb[j]);
  }
  if (p < s1){
    int sa = eidx[p];
    float wa = b2f(pbuf[(long)p*H + h]);
    s16x8 va = *(const s16x8*)&xin[(long)sa*ldx + c0];
#pragma unroll
    for (int j = 0; j < 8; ++j) acc[j] += wa*b2f((u16)va[j]);
  }
  float inv = invd[(long)i*H + h];
  s16x8 ov;
#pragma unroll
  for (int j = 0; j < 8; ++j) ov[j] = (short)f2bf(acc[j]*inv);
  *(s16x8*)&xagg[(long)i*ldagg + h*headStride + c0] = ov;
}

__global__ void pack_pool(const u32* __restrict__ poolf, u16* __restrict__ pooled, int n){
  int i = blockIdx.x*256 + threadIdx.x;
  if (i >= n) return;
  u32 b = poolf[i]; float f; __builtin_memcpy(&f, &b, 4);
  pooled[i] = f2bf(f);
}

// ---------------------------------------------------------------------------
// Multi-head batched GEMM (NH compile-time). NH=1 folds head math away
// (84 VGPR -> 6 blocks/CU — R9-verified). 1D grid, XCD-aware decode. BK=32.
// mode bit0: bias+relu; bit1: store dtype per flags[0]; bit2: fused graph-max-pool.
template<int NH>
__global__ __launch_bounds__(256) void gemm_bt(
    const u16* __restrict__ Ag, long lda, const u16* __restrict__ Bg,
    const u16* __restrict__ bias, u16* __restrict__ Cg,
    int M, int Nstore, int K, long ldc, int mode, const int* flags,
    const int* __restrict__ batg, u32* poolf, long ldp,
    int nt, int mt, long hA, long hB, long hC)
{
  const int xcd = blockIdx.x & 7;
  const int g = blockIdx.x >> 3;
  const u16 *A, *B, *bi; u16* C;
  int ntile, m;
  if constexpr (NH > 1){
    const int nhnt = NH * nt;
    const int inner = g % nhnt;
    ntile = inner % nt;
    const int head = inner / nt;
    m = (g / nhnt)*8 + xcd;
    A = Ag + (long)head*hA; B = Bg + (long)head*hB;
    bi = bias + (long)head*hC; C = Cg + (long)head*hC;
  } else {
    ntile = g % nt;
    m = (g / nt)*8 + xcd;
    A = Ag; B = Bg; bi = bias; C = Cg;
  }
  if (m >= mt) return;

  __shared__ __align__(16) u16 As[128*32];
  __shared__ __align__(16) u16 Bs[128*32];
  const int tid = threadIdx.x;
  const int wave = tid >> 6, lane = tid & 63;
  const int quad = lane >> 4, mrow = lane & 15;
  const int wm = (wave >> 1) * 64, wn = (wave & 1) * 64;
  const long bm = (long)m * 128;
  const long bn = (long)ntile * 128;

  f32x4 acc[4][4];
#pragma unroll
  for (int i = 0; i < 4; i++)
#pragma unroll
    for (int j = 0; j < 4; j++) acc[i][j] = (f32x4){0.f, 0.f, 0.f, 0.f};

  const int r0 = wave*32 + (lane >> 2);
  const int r1 = r0 + 16;
  const int kcl = lane & 3;
  const int q0 = kcl ^ ((r0 >> 1) & 3);
  const int q1 = kcl ^ ((r1 >> 1) & 3);
  const u16* a0 = A + (bm + r0)*lda + q0*8;
  const u16* a1 = A + (bm + r1)*lda + q1*8;
  const u16* b0 = B + (bn + r0)*(long)K + q0*8;
  const u16* b1 = B + (bn + r1)*(long)K + q1*8;
  u16* la0 = &As[r0*32 + kcl*8];
  u16* la1 = &As[r1*32 + kcl*8];
  u16* lb0 = &Bs[r0*32 + kcl*8];
  u16* lb1 = &Bs[r1*32 + kcl*8];

  for (int k0 = 0; k0 < K; k0 += 32){
    async16(a0 + k0, la0);
    async16(a1 + k0, la1);
    async16(b0 + k0, lb0);
    async16(b1 + k0, lb1);
    __syncthreads();
    s16x8 af[4], bf[4];
#pragma unroll
    for (int i = 0; i < 4; i++){
      int r = wm + i*16 + mrow;
      int q = quad ^ ((r >> 1) & 3);
      af[i] = *(const s16x8*)&As[r*32 + q*8];
    }
#pragma unroll
    for (int j = 0; j < 4; j++){
      int r = wn + j*16 + mrow;
      int q = quad ^ ((r >> 1) & 3);
      bf[j] = *(const s16x8*)&Bs[r*32 + q*8];
    }
#pragma unroll
    for (int i = 0; i < 4; i++)
#pragma unroll
      for (int j = 0; j < 4; j++)
        acc[i][j] = __builtin_amdgcn_mfma_f32_16x16x32_bf16(af[i], bf[j], acc[i][j], 0, 0, 0);
    __syncthreads();
  }

  if (mode & 4){
    int garr[16];
#pragma unroll
    for (int i = 0; i < 4; i++)
#pragma unroll
      for (int r = 0; r < 4; r++){
        long row = bm + wm + i*16 + quad*4 + r;
        garr[i*4+r] = (row < M) ? batg[row] : -1;
      }
#pragma unroll
    for (int j = 0; j < 4; j++){
      long col = bn + wn + j*16 + mrow;
      if (col >= Nstore) continue;
      float bv = b2f(bi[col]);
      int curg = -1; float curm = 0.f;
#pragma unroll
      for (int i = 0; i < 4; i++)
#pragma unroll
        for (int r = 0; r < 4; r++){
          int g2 = garr[i*4+r];
          if (g2 >= 0){
            float v = fmaxf(acc[i][j][r] + bv, 0.f);
            if (g2 != curg){
              if (curg >= 0){
                u32 bits; __builtin_memcpy(&bits, &curm, 4);
                atomicMax(&poolf[(long)curg*ldp + col], bits);
              }
              curg = g2; curm = v;
            } else curm = fmaxf(curm, v);
          }
        }
      if (curg >= 0){
        u32 bits; __builtin_memcpy(&bits, &curm, 4);
        atomicMax(&poolf[(long)curg*ldp + col], bits);
      }
    }
    return;
  }

  const int f0 = (mode & 2) ? flags[0] : 1;
#pragma unroll
  for (int i = 0; i < 4; i++){
    long row0 = bm + wm + i*16 + quad*4;
#pragma unroll
    for (int j = 0; j < 4; j++){
      long col = bn + wn + j*16 + mrow;
      if (col < Nstore){
        float bv = (mode & 1) ? b2f(bi[col]) : 0.f;
#pragma unroll
        for (int r = 0; r < 4; r++){
          long row = row0 + r;
          if (row < M){
            float v = acc[i][j][r];
            if (mode & 1) v = fmaxf(v + bv, 0.f);
            if (f0) C[row*ldc + col] = f2bf(v);
            else    ((float*)C)[row*ldc + col] = v;
          }
        }
      }
    }
  }
}

// ---------------------------------------------------------------------------
extern "C" void kernel_launch(void* const* d_in, const int* in_sizes, int n_in,
                              void* d_out, int out_size, void* d_ws, size_t ws_size,
                              hipStream_t stream){
  const u16* x    = (const u16*)d_in[0];
  const int* ei   = (const int*)d_in[1];
  const int* bat  = (const int*)d_in[2];
  const void* W1  = d_in[3];
  const void* as1 = d_in[4]; const void* ad1 = d_in[5]; const void* b1 = d_in[6];
  const void* W2  = d_in[7];
  const void* as2 = d_in[8]; const void* ad2 = d_in[9]; const void* b2 = d_in[10];
  const void* W3  = d_in[11];
  const void* as3 = d_in[12]; const void* ad3 = d_in[13]; const void* b3 = d_in[14];
  const void* fc1w = d_in[15]; const void* fc1b = d_in[16];
  const void* fc2w = d_in[17]; const void* fc2b = d_in[18];

  const int E = in_sizes[1] / 2;
  const int N = in_sizes[2];
  const int G = 512, H = 4;
  const int Mpad = ((N + 127)/128)*128;
  const int Etot = E + N;
  const int Mt = Mpad/128;                 // 391
  const int nb1024 = (N + 1023)/1024;
  const int Mg8 = ((Mt + 7)/8);            // 49

  char* w = (char*)d_ws;
  size_t off = 0;
  auto AL = [&](size_t b)->char*{ char* p = w + off; off = (off + b + 255) & ~(size_t)255; return p; };

  u16* P = (u16*)AL((size_t)Mpad*1248*2 + 512);
  u16* Q = (u16*)AL((size_t)Mpad*1248*2 + 512);
  u16* wt1 = (u16*)AL((size_t)4*128*96*2);
  u16* wt2 = (u16*)AL((size_t)4*384*320*2);
  u16* wt3 = (u16*)AL((size_t)1280*1248*2);
  u16* wf1 = (u16*)AL((size_t)1024*1248*2);
  u16* wf2 = (u16*)AL((size_t)128*1024*2);
  u16* cb1 = (u16*)AL(312*2);  u16* cb2 = (u16*)AL(1248*2); u16* cb3 = (u16*)AL(1248*2);
  u16* cbf1 = (u16*)AL(1024*2); u16* cbf2 = (u16*)AL(128*2);
  float* ws1 = (float*)AL(4*80*4);   float* wd1 = (float*)AL(4*80*4);
  float* ws2 = (float*)AL(4*312*4);  float* wd2 = (float*)AL(4*312*4);
  float* ws3 = (float*)AL(1248*4);   float* wd3 = (float*)AL(1248*4);
  float* a_src = (float*)AL((size_t)N*H*4);
  float* a_dst = (float*)AL((size_t)N*H*4);
  float* invd  = (float*)AL((size_t)N*H*4);
  u16*  pbuf   = (u16*)AL((size_t)Etot*H*2);
  u32* cnt     = (u32*)AL((size_t)N*4);
  u32* rowptr  = (u32*)AL((size_t)(N+1)*4);
  u32* bsum    = (u32*)AL((size_t)1024*4);
  u32* boff    = (u32*)AL((size_t)1024*4);
  int* eidx    = (int*)AL((size_t)Etot*4);
  int* bat32   = (int*)AL((size_t)N*4);
  u32* poolf   = (u32*)AL((size_t)G*1248*4);
  u16* pooled  = (u16*)AL((size_t)G*1248*2 + 512);
  u16* fc1o    = (u16*)AL((size_t)G*1024*2 + 512);
  int* flags   = (int*)AL(16);

  if (ws_size < off || n_in < 19) return;

  u16* xpad = (u16*)((char*)P + ((size_t)40 << 20));
  int* rowC = (int*)((char*)Q + ((size_t)64 << 20));
  int* colC = rowC + E;

  // ---- ingest ----
  detect_flags<<<1, 64, 0, stream>>>(x, ei, flags);
  zero_u32<<<(N+255)/256, 256, 0, stream>>>(cnt, N);
  zero_u32<<<(G*1248+255)/256, 256, 0, stream>>>(poolf, G*1248);
  {
    long tot = (long)Mpad*96;
    pad_copy_x<<<(unsigned)((tot+255)/256), 256, 0, stream>>>(x, xpad, N, tot, 78, 96, flags);
  }
  for (int h = 0; h < 4; ++h)
    transpose_pad<<<dim3(3,4),  256, 0, stream>>>(W1, wt1 + h*128*96, 78, 78, 96, 128, 312, h*78, flags);
  for (int h = 0; h < 4; ++h)
    transpose_pad<<<dim3(10,12), 256, 0, stream>>>(W2, wt2 + h*384*320, 312, 312, 320, 384, 1248, h*312, flags);
  transpose_pad<<<dim3(39,40), 256, 0, stream>>>(W3,   wt3, 1248, 1248, 1248, 1280, 1248, 0, flags);
  transpose_pad<<<dim3(39,32), 256, 0, stream>>>(fc1w, wf1, 1248, 1024, 1248, 1024, 1024, 0, flags);
  transpose_pad<<<dim3(32,4),  256, 0, stream>>>(fc2w, wf2, 1024, 128,  1024, 128,  128,  0, flags);
  copy_vec5<<<(312+1248+1248+1024+128+255)/256, 256, 0, stream>>>(
      b1, cb1, 312, b2, cb2, 1248, b3, cb3, 1248, fc1b, cbf1, 1024, fc2b, cbf2, 128, flags);
  copy_int3<<<(E+E+N+255)/256, 256, 0, stream>>>(ei, bat, rowC, colC, bat32, E, N, flags);
  wproj<<<(4*80+3)/4,   256, 0, stream>>>(W1, as1, ad1, ws1, wd1, 78, 80, 78, 312, 4, flags);
  wproj<<<(4*312+3)/4,  256, 0, stream>>>(W2, as2, ad2, ws2, wd2, 312, 312, 312, 1248, 4, flags);
  wproj<<<(1248+3)/4,   256, 0, stream>>>(W3, as3, ad3, ws3, wd3, 1248, 1248, 1248, 1248, 1, flags);

  // ---- CSR ----
  hist_kernel<<<(E+255)/256, 256, 0, stream>>>(colC, cnt, E);
  scan_local<<<nb1024, 1024, 0, stream>>>(cnt, rowptr, bsum, N);
  scan_bsums<<<1, 1024, 0, stream>>>(bsum, boff, nb1024);
  scan_fixup<<<nb1024, 1024, 0, stream>>>(rowptr, boff, N);
  fill_self<<<(N+255)/256, 256, 0, stream>>>(rowptr, eidx, cnt, N);
  fill_edges<<<(E+255)/256, 256, 0, stream>>>(rowC, colC, cnt, eidx, E);

  const int db = (N + 3)/4;

  // ---- conv1: x[N,96] -> xagg1[N,384] -> out1[N,312] in P (4 heads, 1 launch) ----
  attn_dots_v<4><<<db, 256, 0, stream>>>(xpad, 96, ws1, wd1, a_src, a_dst, N, 80);
  attn_stats<<<(N*4+255)/256, 256, 0, stream>>>(rowptr, eidx, a_src, a_dst, pbuf, invd, N*4, 4);
  aggregate_v<<<N, 64, 0, stream>>>(rowptr, eidx, pbuf, invd, xpad, 96, Q, 384, 10, 4, 96);
  gemm_bt<4><<<Mg8*4*1*8, 256, 0, stream>>>(Q, 384, wt1, cb1, P, N, 78, 96, 312, 1, flags,
                                            nullptr, nullptr, 0, 1, Mt, 96, 128*96, 78);

  // ---- conv2: out1 -> xagg2[N,1248] -> out2[N,1248] in P (4 heads, 1 launch) ----
  attn_dots_v<4><<<db, 256, 0, stream>>>(P, 312, ws2, wd2, a_src, a_dst, N, 312);
  attn_stats<<<(N*4+255)/256, 256, 0, stream>>>(rowptr, eidx, a_src, a_dst, pbuf, invd, N*4, 4);
  aggregate_v<<<N, 192, 0, stream>>>(rowptr, eidx, pbuf, invd, P, 312, Q, 1248, 39, 4, 312);
  gemm_bt<4><<<Mg8*4*3*8, 256, 0, stream>>>(Q, 1248, wt2, cb2, P, N, 312, 320, 1248, 1, flags,
                                            nullptr, nullptr, 0, 3, Mt, 312, 384*320, 312);

  // ---- conv3 (H=1): out2 -> xagg3 -> fused GEMM+pool (NH=1: 84-VGPR path) ----
  attn_dots_v<1><<<db, 256, 0, stream>>>(P, 1248, ws3, wd3, a_src, a_dst, N, 1248);
  attn_stats<<<(N+255)/256, 256, 0, stream>>>(rowptr, eidx, a_src, a_dst, pbuf, invd, N, 1);
  aggregate_v<<<N, 192, 0, stream>>>(rowptr, eidx, pbuf, invd, P, 1248, Q, 1248, 156, 1, 0);
  gemm_bt<1><<<Mg8*10*8, 256, 0, stream>>>(Q, 1248, wt3, cb3, P, N, 1248, 1248, 1248, 1|4, flags,
                                           bat32, poolf, 1248, 10, Mt, 0, 0, 0);

  // ---- pool pack + FCs ----
  pack_pool<<<(G*1248+255)/256, 256, 0, stream>>>(poolf, pooled, G*1248);
  gemm_bt<1><<<64, 256, 0, stream>>>(pooled, 1248, wf1, cbf1, fc1o, G, 1024, 1248, 1024, 1, flags,
                                     nullptr, nullptr, 0, 8, 4, 0, 0, 0);
  gemm_bt<1><<<8, 256, 0, stream>>>(fc1o, 1024, wf2, cbf2, (u16*)d_out, G, 128, 1024, 128, 3, flags,
                                    nullptr, nullptr, 0, 1, 4, 0, 0, 0);
}